// Round 1
// baseline (58704.974 us; speedup 1.0000x reference)
//
#include <hip/hip_runtime.h>
#include <hip/hip_bf16.h>

// Problem constants (from reference)
constexpr int N_NODES = 100000;
constexpr int N_EDGES = 3200000;
constexpr int N_PAIRS = 500000;
constexpr int D       = 256;     // D_IN == D_HID

// ---------------------------------------------------------------------------
// agg = src buffer copy (float4 grid-stride)
// ---------------------------------------------------------------------------
__global__ void copy_f4(const float4* __restrict__ in, float4* __restrict__ out, int n4) {
  int i = blockIdx.x * blockDim.x + threadIdx.x;
  int stride = gridDim.x * blockDim.x;
  for (; i < n4; i += stride) out[i] = in[i];
}

// ---------------------------------------------------------------------------
// scatter-add: one wave per edge; lane handles 4 contiguous feature floats.
// agg[dst] += x[src]
// ---------------------------------------------------------------------------
__global__ __launch_bounds__(256) void scatter_add(const float* __restrict__ x,
                                                   const int* __restrict__ ei,
                                                   float* __restrict__ agg) {
  int wave = (int)((blockIdx.x * (size_t)blockDim.x + threadIdx.x) >> 6);
  int lane = threadIdx.x & 63;
  if (wave >= N_EDGES) return;
  int src = ei[wave];
  int dst = ei[N_EDGES + wave];
  const float4 v = *reinterpret_cast<const float4*>(x + (size_t)src * D + lane * 4);
  float* p = agg + (size_t)dst * D + lane * 4;
  atomicAdd(p + 0, v.x);
  atomicAdd(p + 1, v.y);
  atomicAdd(p + 2, v.z);
  atomicAdd(p + 3, v.w);
}

// ---------------------------------------------------------------------------
// C[row][col] = relu( sum_k A[row][k] * W[col][k] + b[col] )
// A: [N_NODES][256], W: [256][256] row-major (output-major), C: [N_NODES][256]
// Block: 256 threads -> 64 rows x 64 cols tile; K staged in chunks of 64.
// LDS transposed with stride 68 (16B-aligned, low-conflict float4 reads).
// ---------------------------------------------------------------------------
__global__ __launch_bounds__(256) void gemm_bias_relu(const float* __restrict__ A,
                                                      const float* __restrict__ W,
                                                      const float* __restrict__ b,
                                                      float* __restrict__ C) {
  __shared__ float As[64][68];  // [k][row]
  __shared__ float Ws[64][68];  // [k][col]

  const int t  = threadIdx.x;
  const int tx = t & 15;   // col group (0..15)
  const int ty = t >> 4;   // row group (0..15)
  const int kk = t & 63;
  const int rb = t >> 6;   // 0..3

  const int row0 = blockIdx.x * 64;
  const int col0 = blockIdx.y * 64;

  float acc[4][4];
#pragma unroll
  for (int i = 0; i < 4; ++i)
#pragma unroll
    for (int j = 0; j < 4; ++j) acc[i][j] = 0.f;

#pragma unroll
  for (int kc = 0; kc < 4; ++kc) {
    const int k0 = kc * 64;
    // stage A (guarded) and W, transposed into LDS
#pragma unroll
    for (int i = 0; i < 16; ++i) {
      const int r = rb * 16 + i;          // 0..63
      const int grow = row0 + r;
      float av = (grow < N_NODES) ? A[(size_t)grow * D + k0 + kk] : 0.f;
      As[kk][r] = av;
      Ws[kk][r] = W[(size_t)(col0 + r) * D + k0 + kk];
    }
    __syncthreads();
#pragma unroll
    for (int k = 0; k < 64; ++k) {
      const float4 a4 = *reinterpret_cast<const float4*>(&As[k][ty * 4]);
      const float4 w4 = *reinterpret_cast<const float4*>(&Ws[k][tx * 4]);
      const float a[4] = {a4.x, a4.y, a4.z, a4.w};
      const float w[4] = {w4.x, w4.y, w4.z, w4.w};
#pragma unroll
      for (int i = 0; i < 4; ++i)
#pragma unroll
        for (int j = 0; j < 4; ++j) acc[i][j] += a[i] * w[j];
    }
    __syncthreads();
  }

  const float4 bv = *reinterpret_cast<const float4*>(&b[col0 + tx * 4]);
  const float bb[4] = {bv.x, bv.y, bv.z, bv.w};
#pragma unroll
  for (int i = 0; i < 4; ++i) {
    const int grow = row0 + ty * 4 + i;
    if (grow < N_NODES) {
      float4 o;
      o.x = fmaxf(acc[i][0] + bb[0], 0.f);
      o.y = fmaxf(acc[i][1] + bb[1], 0.f);
      o.z = fmaxf(acc[i][2] + bb[2], 0.f);
      o.w = fmaxf(acc[i][3] + bb[3], 0.f);
      *reinterpret_cast<float4*>(&C[(size_t)grow * D + col0 + tx * 4]) = o;
    }
  }
}

// ---------------------------------------------------------------------------
// Pair head: one wave per pair. logits = [h[i0]|h[i1]] @ W3^T + b3 ; log_softmax
// W3: [2][512] row-major. out: [P][2] f32.
// ---------------------------------------------------------------------------
__global__ __launch_bounds__(256) void pair_head(const float* __restrict__ h,
                                                 const int* __restrict__ idx,
                                                 const float* __restrict__ W3,
                                                 const float* __restrict__ b3,
                                                 float* __restrict__ out) {
  int wave = (int)((blockIdx.x * (size_t)blockDim.x + threadIdx.x) >> 6);
  int lane = threadIdx.x & 63;
  if (wave >= N_PAIRS) return;
  const int i0 = idx[2 * wave + 0];
  const int i1 = idx[2 * wave + 1];

  const float4 a  = *reinterpret_cast<const float4*>(h + (size_t)i0 * D + lane * 4);
  const float4 c  = *reinterpret_cast<const float4*>(h + (size_t)i1 * D + lane * 4);
  const float4 w0a = *reinterpret_cast<const float4*>(W3 + 0   + lane * 4);
  const float4 w0b = *reinterpret_cast<const float4*>(W3 + 256 + lane * 4);
  const float4 w1a = *reinterpret_cast<const float4*>(W3 + 512 + lane * 4);
  const float4 w1b = *reinterpret_cast<const float4*>(W3 + 768 + lane * 4);

  float l0 = a.x * w0a.x + a.y * w0a.y + a.z * w0a.z + a.w * w0a.w
           + c.x * w0b.x + c.y * w0b.y + c.z * w0b.z + c.w * w0b.w;
  float l1 = a.x * w1a.x + a.y * w1a.y + a.z * w1a.z + a.w * w1a.w
           + c.x * w1b.x + c.y * w1b.y + c.z * w1b.z + c.w * w1b.w;

#pragma unroll
  for (int off = 32; off > 0; off >>= 1) {
    l0 += __shfl_down(l0, off, 64);
    l1 += __shfl_down(l1, off, 64);
  }
  if (lane == 0) {
    l0 += b3[0];
    l1 += b3[1];
    const float m = fmaxf(l0, l1);
    const float lse = m + logf(expf(l0 - m) + expf(l1 - m));
    out[2 * (size_t)wave + 0] = l0 - lse;
    out[2 * (size_t)wave + 1] = l1 - lse;
  }
}

// ---------------------------------------------------------------------------
extern "C" void kernel_launch(void* const* d_in, const int* in_sizes, int n_in,
                              void* d_out, int out_size, void* d_ws, size_t ws_size,
                              hipStream_t stream) {
  const float* x   = (const float*)d_in[0];
  const int*   ei  = (const int*)d_in[1];
  const int*   idx = (const int*)d_in[2];
  const float* W1  = (const float*)d_in[3];
  const float* b1  = (const float*)d_in[4];
  const float* W2  = (const float*)d_in[5];
  const float* b2  = (const float*)d_in[6];
  const float* W3  = (const float*)d_in[7];
  const float* b3  = (const float*)d_in[8];
  float* out = (float*)d_out;

  const size_t feat_elems = (size_t)N_NODES * D;   // 25.6M floats
  float* bufA = (float*)d_ws;                      // agg buffer
  float* bufB = bufA + feat_elems;                 // h buffer

  const int n4 = (int)(feat_elems / 4);
  const dim3 copyGrid(4096), blk(256);
  const dim3 scatGrid((N_EDGES * 64 + 255) / 256);
  const dim3 gemmGrid((N_NODES + 63) / 64, D / 64);
  const dim3 pairGrid((N_PAIRS * 64 + 255) / 256);

  // ---- layer 1: agg1 = x + scatter(x); h1 = relu(agg1 @ W1^T + b1) ----
  copy_f4<<<copyGrid, blk, 0, stream>>>((const float4*)x, (float4*)bufA, n4);
  scatter_add<<<scatGrid, blk, 0, stream>>>(x, ei, bufA);
  gemm_bias_relu<<<gemmGrid, blk, 0, stream>>>(bufA, W1, b1, bufB);

  // ---- layer 2: agg2 = h1 + scatter(h1); h2 = relu(agg2 @ W2^T + b2) ----
  copy_f4<<<copyGrid, blk, 0, stream>>>((const float4*)bufB, (float4*)bufA, n4);
  scatter_add<<<scatGrid, blk, 0, stream>>>(bufB, ei, bufA);
  gemm_bias_relu<<<gemmGrid, blk, 0, stream>>>(bufA, W2, b2, bufB);

  // ---- pair head ----
  pair_head<<<pairGrid, blk, 0, stream>>>(bufB, idx, W3, b3, out);
}

// Round 2
// 1978.842 us; speedup vs baseline: 29.6663x; 29.6663x over previous
//
#include <hip/hip_runtime.h>
#include <hip/hip_bf16.h>

constexpr int N_NODES = 100000;
constexpr int N_EDGES = 3200000;
constexpr int N_PAIRS = 500000;
constexpr int D       = 256;

// ---------------------------------------------------------------------------
__global__ void zero_ints(int* __restrict__ p, int n) {
  int i = blockIdx.x * blockDim.x + threadIdx.x;
  if (i < n) p[i] = 0;
}

// counts[dst]++
__global__ void hist_kernel(const int* __restrict__ ei, int* __restrict__ counts) {
  int i = blockIdx.x * blockDim.x + threadIdx.x;
  if (i < N_EDGES) atomicAdd(&counts[ei[N_EDGES + i]], 1);
}

// exclusive prefix sum of counts -> cursor (single block, 1024 threads)
__global__ __launch_bounds__(1024) void scan_kernel(const int* __restrict__ counts,
                                                    int* __restrict__ cursor, int n) {
  __shared__ int wsum[16];
  __shared__ int carry;
  const int t = threadIdx.x, lane = t & 63, w = t >> 6;
  if (t == 0) carry = 0;
  __syncthreads();
  for (int base = 0; base < n; base += 1024) {
    int v = (base + t < n) ? counts[base + t] : 0;
    int s = v;
#pragma unroll
    for (int off = 1; off < 64; off <<= 1) {
      int u = __shfl_up(s, off, 64);
      if (lane >= off) s += u;
    }
    if (lane == 63) wsum[w] = s;
    __syncthreads();
    if (t < 16) {
      int ws = wsum[t];
#pragma unroll
      for (int off = 1; off < 16; off <<= 1) {
        int u = __shfl_up(ws, off, 64);
        if (lane >= off) ws += u;
      }
      wsum[t] = ws;
    }
    __syncthreads();
    const int wpre = (w == 0) ? 0 : wsum[w - 1];
    if (base + t < n) cursor[base + t] = carry + wpre + s - v;  // exclusive
    __syncthreads();
    if (t == 0) carry += wsum[15];
    __syncthreads();
  }
}

// csr[pos] = src, pos = cursor[dst]++  (after this, cursor[i] == end offset of node i)
__global__ void fill_kernel(const int* __restrict__ ei, int* __restrict__ cursor,
                            int* __restrict__ csr) {
  int i = blockIdx.x * blockDim.x + threadIdx.x;
  if (i < N_EDGES) {
    const int src = ei[i];
    const int dst = ei[N_EDGES + i];
    const int pos = atomicAdd(&cursor[dst], 1);
    csr[pos] = src;
  }
}

// out[node] = x[node] + sum_{s in csr[beg:end)} x[s]   (one wave per node)
__global__ __launch_bounds__(256) void gather_agg(const float* __restrict__ x,
                                                  const int* __restrict__ csr,
                                                  const int* __restrict__ cursor_end,
                                                  const int* __restrict__ counts,
                                                  float* __restrict__ out) {
  const int node = blockIdx.x * 4 + (threadIdx.x >> 6);
  const int lane = threadIdx.x & 63;
  if (node >= N_NODES) return;
  const int end = cursor_end[node];
  const int beg = end - counts[node];
  const size_t fo = (size_t)lane * 4;

  float4 acc = *reinterpret_cast<const float4*>(x + (size_t)node * D + fo);
  int o = beg;
  for (; o + 4 <= end; o += 4) {
    const int s0 = csr[o], s1 = csr[o + 1], s2 = csr[o + 2], s3 = csr[o + 3];
    const float4 v0 = *reinterpret_cast<const float4*>(x + (size_t)s0 * D + fo);
    const float4 v1 = *reinterpret_cast<const float4*>(x + (size_t)s1 * D + fo);
    const float4 v2 = *reinterpret_cast<const float4*>(x + (size_t)s2 * D + fo);
    const float4 v3 = *reinterpret_cast<const float4*>(x + (size_t)s3 * D + fo);
    acc.x += v0.x + v1.x + v2.x + v3.x;
    acc.y += v0.y + v1.y + v2.y + v3.y;
    acc.z += v0.z + v1.z + v2.z + v3.z;
    acc.w += v0.w + v1.w + v2.w + v3.w;
  }
  for (; o < end; ++o) {
    const int s = csr[o];
    const float4 v = *reinterpret_cast<const float4*>(x + (size_t)s * D + fo);
    acc.x += v.x; acc.y += v.y; acc.z += v.z; acc.w += v.w;
  }
  *reinterpret_cast<float4*>(out + (size_t)node * D + fo) = acc;
}

// ---------------------------------------------------------------------------
// C[row][col] = relu( sum_k A[row][k]*W[col][k] + b[col] )
// Block: 256 threads, tile 64 rows x 128 cols, per-thread 4x8. K chunks of 64.
// ---------------------------------------------------------------------------
__global__ __launch_bounds__(256, 4) void gemm_bias_relu(const float* __restrict__ A,
                                                         const float* __restrict__ W,
                                                         const float* __restrict__ b,
                                                         float* __restrict__ C) {
  __shared__ float As[64][68];    // [k][row]
  __shared__ float Ws[64][132];   // [k][col]

  const int t  = threadIdx.x;
  const int tx = t & 15;    // col group: 8 cols at tx*8
  const int ty = t >> 4;    // row group: 4 rows at ty*4
  const int kk = t & 63;
  const int rb = t >> 6;

  const int row0 = blockIdx.x * 64;
  const int col0 = blockIdx.y * 128;

  float acc[4][8];
#pragma unroll
  for (int i = 0; i < 4; ++i)
#pragma unroll
    for (int j = 0; j < 8; ++j) acc[i][j] = 0.f;

  for (int kc = 0; kc < 4; ++kc) {
    const int k0 = kc * 64;
#pragma unroll
    for (int i = 0; i < 16; ++i) {
      const int r = rb * 16 + i;
      const int grow = row0 + r;
      As[kk][r] = (grow < N_NODES) ? A[(size_t)grow * D + k0 + kk] : 0.f;
    }
#pragma unroll
    for (int i = 0; i < 32; ++i) {
      const int c = rb * 32 + i;
      Ws[kk][c] = W[(size_t)(col0 + c) * D + k0 + kk];
    }
    __syncthreads();
#pragma unroll 16
    for (int k = 0; k < 64; ++k) {
      const float4 a4  = *reinterpret_cast<const float4*>(&As[k][ty * 4]);
      const float4 wa  = *reinterpret_cast<const float4*>(&Ws[k][tx * 8]);
      const float4 wb  = *reinterpret_cast<const float4*>(&Ws[k][tx * 8 + 4]);
      const float a[4] = {a4.x, a4.y, a4.z, a4.w};
      const float w[8] = {wa.x, wa.y, wa.z, wa.w, wb.x, wb.y, wb.z, wb.w};
#pragma unroll
      for (int i = 0; i < 4; ++i)
#pragma unroll
        for (int j = 0; j < 8; ++j) acc[i][j] += a[i] * w[j];
    }
    __syncthreads();
  }

  const float4 ba = *reinterpret_cast<const float4*>(&b[col0 + tx * 8]);
  const float4 bb = *reinterpret_cast<const float4*>(&b[col0 + tx * 8 + 4]);
  const float bias[8] = {ba.x, ba.y, ba.z, ba.w, bb.x, bb.y, bb.z, bb.w};
#pragma unroll
  for (int i = 0; i < 4; ++i) {
    const int grow = row0 + ty * 4 + i;
    if (grow < N_NODES) {
      float4 o1, o2;
      o1.x = fmaxf(acc[i][0] + bias[0], 0.f);
      o1.y = fmaxf(acc[i][1] + bias[1], 0.f);
      o1.z = fmaxf(acc[i][2] + bias[2], 0.f);
      o1.w = fmaxf(acc[i][3] + bias[3], 0.f);
      o2.x = fmaxf(acc[i][4] + bias[4], 0.f);
      o2.y = fmaxf(acc[i][5] + bias[5], 0.f);
      o2.z = fmaxf(acc[i][6] + bias[6], 0.f);
      o2.w = fmaxf(acc[i][7] + bias[7], 0.f);
      float* cp = C + (size_t)grow * D + col0 + tx * 8;
      *reinterpret_cast<float4*>(cp)     = o1;
      *reinterpret_cast<float4*>(cp + 4) = o2;
    }
  }
}

// ---------------------------------------------------------------------------
// Pair head: one wave per pair.
// ---------------------------------------------------------------------------
__global__ __launch_bounds__(256) void pair_head(const float* __restrict__ h,
                                                 const int* __restrict__ idx,
                                                 const float* __restrict__ W3,
                                                 const float* __restrict__ b3,
                                                 float* __restrict__ out) {
  const int wave = (int)((blockIdx.x * (size_t)blockDim.x + threadIdx.x) >> 6);
  const int lane = threadIdx.x & 63;
  if (wave >= N_PAIRS) return;
  const int i0 = idx[2 * wave + 0];
  const int i1 = idx[2 * wave + 1];

  const float4 a   = *reinterpret_cast<const float4*>(h + (size_t)i0 * D + lane * 4);
  const float4 c   = *reinterpret_cast<const float4*>(h + (size_t)i1 * D + lane * 4);
  const float4 w0a = *reinterpret_cast<const float4*>(W3 + 0   + lane * 4);
  const float4 w0b = *reinterpret_cast<const float4*>(W3 + 256 + lane * 4);
  const float4 w1a = *reinterpret_cast<const float4*>(W3 + 512 + lane * 4);
  const float4 w1b = *reinterpret_cast<const float4*>(W3 + 768 + lane * 4);

  float l0 = a.x * w0a.x + a.y * w0a.y + a.z * w0a.z + a.w * w0a.w
           + c.x * w0b.x + c.y * w0b.y + c.z * w0b.z + c.w * w0b.w;
  float l1 = a.x * w1a.x + a.y * w1a.y + a.z * w1a.z + a.w * w1a.w
           + c.x * w1b.x + c.y * w1b.y + c.z * w1b.z + c.w * w1b.w;

#pragma unroll
  for (int off = 32; off > 0; off >>= 1) {
    l0 += __shfl_down(l0, off, 64);
    l1 += __shfl_down(l1, off, 64);
  }
  if (lane == 0) {
    l0 += b3[0];
    l1 += b3[1];
    const float m = fmaxf(l0, l1);
    const float lse = m + logf(expf(l0 - m) + expf(l1 - m));
    out[2 * (size_t)wave + 0] = l0 - lse;
    out[2 * (size_t)wave + 1] = l1 - lse;
  }
}

// ---------------------------------------------------------------------------
extern "C" void kernel_launch(void* const* d_in, const int* in_sizes, int n_in,
                              void* d_out, int out_size, void* d_ws, size_t ws_size,
                              hipStream_t stream) {
  const float* x   = (const float*)d_in[0];
  const int*   ei  = (const int*)d_in[1];
  const int*   idx = (const int*)d_in[2];
  const float* W1  = (const float*)d_in[3];
  const float* b1  = (const float*)d_in[4];
  const float* W2  = (const float*)d_in[5];
  const float* b2  = (const float*)d_in[6];
  const float* W3  = (const float*)d_in[7];
  const float* b3  = (const float*)d_in[8];
  float* out = (float*)d_out;

  const size_t feat = (size_t)N_NODES * D;
  float* bufA  = (float*)d_ws;          // aggregated features [N][256]
  float* bufB  = bufA + feat;           // hidden activations  [N][256]
  int* counts  = (int*)(bufB + feat);   // [N]
  int* cursor  = counts + N_NODES;      // [N] (excl offsets -> end offsets)
  int* csr     = cursor + N_NODES;      // [E] src indices grouped by dst

  const dim3 blk(256);
  const dim3 zeroGrid((N_NODES + 255) / 256);
  const dim3 edgeGrid((N_EDGES + 255) / 256);
  const dim3 nodeGrid((N_NODES + 3) / 4);
  const dim3 gemmGrid((N_NODES + 63) / 64, D / 128);
  const dim3 pairGrid(((size_t)N_PAIRS * 64 + 255) / 256);

  // ---- CSR build (per call; edge_index is constant so this is deterministic work) ----
  zero_ints<<<zeroGrid, blk, 0, stream>>>(counts, N_NODES);
  hist_kernel<<<edgeGrid, blk, 0, stream>>>(ei, counts);
  scan_kernel<<<1, 1024, 0, stream>>>(counts, cursor, N_NODES);
  fill_kernel<<<edgeGrid, blk, 0, stream>>>(ei, cursor, csr);

  // ---- layer 1 ----
  gather_agg<<<nodeGrid, blk, 0, stream>>>(x, csr, cursor, counts, bufA);
  gemm_bias_relu<<<gemmGrid, blk, 0, stream>>>(bufA, W1, b1, bufB);

  // ---- layer 2 ----
  gather_agg<<<nodeGrid, blk, 0, stream>>>(bufB, csr, cursor, counts, bufA);
  gemm_bias_relu<<<gemmGrid, blk, 0, stream>>>(bufA, W2, b2, bufB);

  // ---- pair head ----
  pair_head<<<pairGrid, blk, 0, stream>>>(bufB, idx, W3, b3, out);
}

// Round 3
// 1122.755 us; speedup vs baseline: 52.2866x; 1.7625x over previous
//
#include <hip/hip_runtime.h>
#include <hip/hip_bf16.h>

constexpr int N_NODES = 100000;
constexpr int N_EDGES = 3200000;
constexpr int N_PAIRS = 500000;
constexpr int D       = 256;

using frag_ab = __attribute__((ext_vector_type(8))) short;   // 8 bf16
using frag_cd = __attribute__((ext_vector_type(4))) float;   // 4 f32

static __device__ __forceinline__ float b2f(unsigned short u) {
  return __uint_as_float(((unsigned)u) << 16);
}
static __device__ __forceinline__ unsigned short f2bf(float f) {
  unsigned u = __float_as_uint(f);
  unsigned r = (u + 0x7fff + ((u >> 16) & 1)) >> 16;   // RNE
  return (unsigned short)r;
}

// ---------------------------------------------------------------------------
__global__ void zero_ints(int* __restrict__ p, int n) {
  int i = blockIdx.x * blockDim.x + threadIdx.x;
  if (i < n) p[i] = 0;
}

__global__ void f32_to_bf16(const float4* __restrict__ in, ushort4* __restrict__ out, int n4) {
  int i = blockIdx.x * blockDim.x + threadIdx.x;
  int stride = gridDim.x * blockDim.x;
  for (; i < n4; i += stride) {
    const float4 v = in[i];
    ushort4 o;
    o.x = f2bf(v.x); o.y = f2bf(v.y); o.z = f2bf(v.z); o.w = f2bf(v.w);
    out[i] = o;
  }
}

// counts[dst]++
__global__ void hist_kernel(const int* __restrict__ ei, int* __restrict__ counts) {
  int i = blockIdx.x * blockDim.x + threadIdx.x;
  if (i < N_EDGES) atomicAdd(&counts[ei[N_EDGES + i]], 1);
}

// exclusive prefix sum of counts -> cursor (single block, 1024 threads)
__global__ __launch_bounds__(1024) void scan_kernel(const int* __restrict__ counts,
                                                    int* __restrict__ cursor, int n) {
  __shared__ int wsum[16];
  __shared__ int carry;
  const int t = threadIdx.x, lane = t & 63, w = t >> 6;
  if (t == 0) carry = 0;
  __syncthreads();
  for (int base = 0; base < n; base += 1024) {
    int v = (base + t < n) ? counts[base + t] : 0;
    int s = v;
#pragma unroll
    for (int off = 1; off < 64; off <<= 1) {
      int u = __shfl_up(s, off, 64);
      if (lane >= off) s += u;
    }
    if (lane == 63) wsum[w] = s;
    __syncthreads();
    if (t < 16) {
      int ws = wsum[t];
#pragma unroll
      for (int off = 1; off < 16; off <<= 1) {
        int u = __shfl_up(ws, off, 64);
        if (lane >= off) ws += u;
      }
      wsum[t] = ws;
    }
    __syncthreads();
    const int wpre = (w == 0) ? 0 : wsum[w - 1];
    if (base + t < n) cursor[base + t] = carry + wpre + s - v;  // exclusive
    __syncthreads();
    if (t == 0) carry += wsum[15];
    __syncthreads();
  }
}

// csr[pos] = src; after this, cursor[i] == end offset of node i
__global__ void fill_kernel(const int* __restrict__ ei, int* __restrict__ cursor,
                            int* __restrict__ csr) {
  int i = blockIdx.x * blockDim.x + threadIdx.x;
  if (i < N_EDGES) {
    const int src = ei[i];
    const int dst = ei[N_EDGES + i];
    const int pos = atomicAdd(&cursor[dst], 1);
    csr[pos] = src;
  }
}

// out[node] = x[node] + sum_{s in csr} x[s]; bf16 rows, f32 accumulate, bf16 out.
// One wave per node; lane covers 4 features (8 B).
__global__ __launch_bounds__(256) void gather_agg_bf16(const ushort* __restrict__ x,
                                                       const int* __restrict__ csr,
                                                       const int* __restrict__ cursor_end,
                                                       const int* __restrict__ counts,
                                                       ushort* __restrict__ out) {
  const int node = blockIdx.x * 4 + (threadIdx.x >> 6);
  const int lane = threadIdx.x & 63;
  if (node >= N_NODES) return;
  const int end = cursor_end[node];
  const int beg = end - counts[node];
  const size_t fo = (size_t)lane * 4;

  const ushort4 self = *reinterpret_cast<const ushort4*>(x + (size_t)node * D + fo);
  float a0 = b2f(self.x), a1 = b2f(self.y), a2 = b2f(self.z), a3 = b2f(self.w);

  int o = beg;
  for (; o + 4 <= end; o += 4) {
    const int s0 = csr[o], s1 = csr[o + 1], s2 = csr[o + 2], s3 = csr[o + 3];
    const ushort4 v0 = *reinterpret_cast<const ushort4*>(x + (size_t)s0 * D + fo);
    const ushort4 v1 = *reinterpret_cast<const ushort4*>(x + (size_t)s1 * D + fo);
    const ushort4 v2 = *reinterpret_cast<const ushort4*>(x + (size_t)s2 * D + fo);
    const ushort4 v3 = *reinterpret_cast<const ushort4*>(x + (size_t)s3 * D + fo);
    a0 += b2f(v0.x) + b2f(v1.x) + b2f(v2.x) + b2f(v3.x);
    a1 += b2f(v0.y) + b2f(v1.y) + b2f(v2.y) + b2f(v3.y);
    a2 += b2f(v0.z) + b2f(v1.z) + b2f(v2.z) + b2f(v3.z);
    a3 += b2f(v0.w) + b2f(v1.w) + b2f(v2.w) + b2f(v3.w);
  }
  for (; o < end; ++o) {
    const ushort4 v = *reinterpret_cast<const ushort4*>(x + (size_t)csr[o] * D + fo);
    a0 += b2f(v.x); a1 += b2f(v.y); a2 += b2f(v.z); a3 += b2f(v.w);
  }
  ushort4 ov;
  ov.x = f2bf(a0); ov.y = f2bf(a1); ov.z = f2bf(a2); ov.w = f2bf(a3);
  *reinterpret_cast<ushort4*>(out + (size_t)node * D + fo) = ov;
}

// ---------------------------------------------------------------------------
// C[r][c] = relu( sum_k A[r][k]*W[c][k] + bias[c] ), all bf16 in / bf16 out.
// Block 256 thr = 4 waves; tile 64 rows x 64 cols; full K=256 staged in LDS
// with XOR swizzle (byte ^ ((row&7)<<4)) for conflict-free ds_read_b128.
// ---------------------------------------------------------------------------
__global__ __launch_bounds__(256) void gemm_mfma_bf16(const ushort* __restrict__ A,
                                                      const ushort* __restrict__ W,
                                                      const float* __restrict__ bias,
                                                      ushort* __restrict__ C,
                                                      int M) {
  __shared__ __align__(16) ushort As[64 * 256];
  __shared__ __align__(16) ushort Ws[64 * 256];

  const int t = threadIdx.x;
  const int w = t >> 6, l = t & 63;
  const int row0 = blockIdx.x * 64;
  const int col0 = blockIdx.y * 64;

  // stage: 64 rows x 512 B each for A and W; 2048 16B-chunks / matrix
  {
    const float4 zero4 = {0.f, 0.f, 0.f, 0.f};
#pragma unroll
    for (int i = 0; i < 8; ++i) {
      const int chunk = t + i * 256;
      const int r  = chunk >> 5;           // 0..63
      const int kb = (chunk & 31) << 4;    // byte offset within row
      const int swz = kb ^ ((r & 7) << 4);
      const int grow = row0 + r;
      float4 av = zero4;
      if (grow < M)
        av = *reinterpret_cast<const float4*>(
            reinterpret_cast<const char*>(A) + (size_t)grow * 512 + kb);
      *reinterpret_cast<float4*>(reinterpret_cast<char*>(As) + r * 512 + swz) = av;
      const float4 wv = *reinterpret_cast<const float4*>(
          reinterpret_cast<const char*>(W) + (size_t)(col0 + r) * 512 + kb);
      *reinterpret_cast<float4*>(reinterpret_cast<char*>(Ws) + r * 512 + swz) = wv;
    }
  }
  __syncthreads();

  const int g  = l >> 4;   // K-group 0..3
  const int fr = l & 15;   // fragment row (A) / col (B) index

  frag_cd acc[4];
#pragma unroll
  for (int c = 0; c < 4; ++c) {
    acc[c][0] = 0.f; acc[c][1] = 0.f; acc[c][2] = 0.f; acc[c][3] = 0.f;
  }

  const int arow = w * 16 + fr;
  const char* Asb = reinterpret_cast<const char*>(As);
  const char* Wsb = reinterpret_cast<const char*>(Ws);
#pragma unroll
  for (int ks = 0; ks < 8; ++ks) {
    const int kb = ks * 64 + g * 16;      // 8 bf16 along K, 16 B
    const frag_ab af = *reinterpret_cast<const frag_ab*>(
        Asb + arow * 512 + (kb ^ ((arow & 7) << 4)));
#pragma unroll
    for (int c = 0; c < 4; ++c) {
      const int wrow = c * 16 + fr;
      const frag_ab bf = *reinterpret_cast<const frag_ab*>(
          Wsb + wrow * 512 + (kb ^ ((wrow & 7) << 4)));
      acc[c] = __builtin_amdgcn_mfma_f32_16x16x32_bf16(af, bf, acc[c], 0, 0, 0);
    }
  }
  __syncthreads();  // done reading As/Ws; reuse As as C tile

  // epilogue: bias+relu -> bf16 -> LDS [64][64] -> coalesced global store
  ushort* Ct = As;
#pragma unroll
  for (int c = 0; c < 4; ++c) {
    const int col = c * 16 + fr;
    const float bv = bias[col0 + col];
#pragma unroll
    for (int r = 0; r < 4; ++r) {
      const int rl = w * 16 + g * 4 + r;   // D layout: row=(lane>>4)*4+reg
      Ct[rl * 64 + col] = f2bf(fmaxf(acc[c][r] + bv, 0.f));
    }
  }
  __syncthreads();
#pragma unroll
  for (int i = 0; i < 2; ++i) {
    const int chunk = t + i * 256;        // 512 chunks: 64 rows x 128 B
    const int r  = chunk >> 3;
    const int cb = (chunk & 7) << 4;
    const int grow = row0 + r;
    if (grow < M)
      *reinterpret_cast<float4*>(reinterpret_cast<char*>(C) + (size_t)grow * 512 + col0 * 2 + cb) =
          *reinterpret_cast<const float4*>(reinterpret_cast<const char*>(Ct) + r * 128 + cb);
  }
}

// ---------------------------------------------------------------------------
// Pair head: one wave per pair; h is bf16, W3/b3 f32, out f32.
// ---------------------------------------------------------------------------
__global__ __launch_bounds__(256) void pair_head_bf16(const ushort* __restrict__ h,
                                                      const int* __restrict__ idx,
                                                      const float* __restrict__ W3,
                                                      const float* __restrict__ b3,
                                                      float* __restrict__ out) {
  const int wave = (int)((blockIdx.x * (size_t)blockDim.x + threadIdx.x) >> 6);
  const int lane = threadIdx.x & 63;
  if (wave >= N_PAIRS) return;
  const int i0 = idx[2 * wave + 0];
  const int i1 = idx[2 * wave + 1];

  const ushort4 a4 = *reinterpret_cast<const ushort4*>(h + (size_t)i0 * D + lane * 4);
  const ushort4 c4 = *reinterpret_cast<const ushort4*>(h + (size_t)i1 * D + lane * 4);
  const float4 w0a = *reinterpret_cast<const float4*>(W3 + 0   + lane * 4);
  const float4 w0b = *reinterpret_cast<const float4*>(W3 + 256 + lane * 4);
  const float4 w1a = *reinterpret_cast<const float4*>(W3 + 512 + lane * 4);
  const float4 w1b = *reinterpret_cast<const float4*>(W3 + 768 + lane * 4);

  const float a0 = b2f(a4.x), a1 = b2f(a4.y), a2 = b2f(a4.z), a3 = b2f(a4.w);
  const float c0 = b2f(c4.x), c1 = b2f(c4.y), c2 = b2f(c4.z), c3 = b2f(c4.w);

  float l0 = a0 * w0a.x + a1 * w0a.y + a2 * w0a.z + a3 * w0a.w
           + c0 * w0b.x + c1 * w0b.y + c2 * w0b.z + c3 * w0b.w;
  float l1 = a0 * w1a.x + a1 * w1a.y + a2 * w1a.z + a3 * w1a.w
           + c0 * w1b.x + c1 * w1b.y + c2 * w1b.z + c3 * w1b.w;

#pragma unroll
  for (int off = 32; off > 0; off >>= 1) {
    l0 += __shfl_down(l0, off, 64);
    l1 += __shfl_down(l1, off, 64);
  }
  if (lane == 0) {
    l0 += b3[0];
    l1 += b3[1];
    const float m = fmaxf(l0, l1);
    const float lse = m + logf(expf(l0 - m) + expf(l1 - m));
    out[2 * (size_t)wave + 0] = l0 - lse;
    out[2 * (size_t)wave + 1] = l1 - lse;
  }
}

// ---------------------------------------------------------------------------
extern "C" void kernel_launch(void* const* d_in, const int* in_sizes, int n_in,
                              void* d_out, int out_size, void* d_ws, size_t ws_size,
                              hipStream_t stream) {
  const float* x   = (const float*)d_in[0];
  const int*   ei  = (const int*)d_in[1];
  const int*   idx = (const int*)d_in[2];
  const float* W1  = (const float*)d_in[3];
  const float* b1  = (const float*)d_in[4];
  const float* W2  = (const float*)d_in[5];
  const float* b2  = (const float*)d_in[6];
  const float* W3  = (const float*)d_in[7];
  const float* b3  = (const float*)d_in[8];
  float* out = (float*)d_out;

  const size_t feat = (size_t)N_NODES * D;  // 25.6M elems
  char* ws = (char*)d_ws;
  ushort* xb    = (ushort*)(ws);                        // 51.2 MB
  ushort* aggb  = (ushort*)(ws + 51200000);             // 51.2 MB
  ushort* hb    = (ushort*)(ws + 102400000);            // 51.2 MB
  ushort* W1b   = (ushort*)(ws + 153600000);            // 128 KB
  ushort* W2b   = (ushort*)(ws + 153731072);            // 128 KB
  int* counts   = (int*)(ws + 153862144);               // 400 KB
  int* cursor   = (int*)(ws + 154262144);               // 400 KB
  int* csr      = (int*)(ws + 154662144);               // 12.8 MB

  const dim3 blk(256);
  const dim3 zeroGrid((N_NODES + 255) / 256);
  const dim3 edgeGrid((N_EDGES + 255) / 256);
  const dim3 nodeGrid((N_NODES + 3) / 4);
  const dim3 gemmGrid((N_NODES + 63) / 64, D / 64);
  const dim3 pairGrid(((size_t)N_PAIRS * 64 + 255) / 256);

  // ---- converts ----
  f32_to_bf16<<<dim3(4096), blk, 0, stream>>>((const float4*)x, (ushort4*)xb, (int)(feat / 4));
  f32_to_bf16<<<dim3(64), blk, 0, stream>>>((const float4*)W1, (ushort4*)W1b, 65536 / 4);
  f32_to_bf16<<<dim3(64), blk, 0, stream>>>((const float4*)W2, (ushort4*)W2b, 65536 / 4);

  // ---- CSR build ----
  zero_ints<<<zeroGrid, blk, 0, stream>>>(counts, N_NODES);
  hist_kernel<<<edgeGrid, blk, 0, stream>>>(ei, counts);
  scan_kernel<<<1, 1024, 0, stream>>>(counts, cursor, N_NODES);
  fill_kernel<<<edgeGrid, blk, 0, stream>>>(ei, cursor, csr);

  // ---- layer 1 ----
  gather_agg_bf16<<<nodeGrid, blk, 0, stream>>>(xb, csr, cursor, counts, aggb);
  gemm_mfma_bf16<<<gemmGrid, blk, 0, stream>>>(aggb, W1b, b1, hb, N_NODES);

  // ---- layer 2 ----
  gather_agg_bf16<<<nodeGrid, blk, 0, stream>>>(hb, csr, cursor, counts, aggb);
  gemm_mfma_bf16<<<gemmGrid, blk, 0, stream>>>(aggb, W2b, b2, hb, N_NODES);

  // ---- pair head ----
  pair_head_bf16<<<pairGrid, blk, 0, stream>>>(hb, idx, W3, b3, out);
}

// Round 4
// 1034.646 us; speedup vs baseline: 56.7392x; 1.0852x over previous
//
#include <hip/hip_runtime.h>
#include <hip/hip_bf16.h>

constexpr int N_NODES = 100000;
constexpr int N_EDGES = 3200000;
constexpr int N_PAIRS = 500000;
constexpr int D       = 256;

using frag_ab = __attribute__((ext_vector_type(8))) short;   // 8 bf16
using frag_cd = __attribute__((ext_vector_type(4))) float;   // 4 f32
typedef unsigned short ushort8 __attribute__((ext_vector_type(8)));

static __device__ __forceinline__ float b2f(unsigned short u) {
  return __uint_as_float(((unsigned)u) << 16);
}
static __device__ __forceinline__ unsigned short f2bf(float f) {
  unsigned u = __float_as_uint(f);
  unsigned r = (u + 0x7fff + ((u >> 16) & 1)) >> 16;   // RNE
  return (unsigned short)r;
}

// ---------------------------------------------------------------------------
__global__ void zero_ints(int* __restrict__ p, int n) {
  int i = blockIdx.x * blockDim.x + threadIdx.x;
  if (i < n) p[i] = 0;
}

__global__ void f32_to_bf16(const float4* __restrict__ in, ushort4* __restrict__ out, int n4) {
  int i = blockIdx.x * blockDim.x + threadIdx.x;
  int stride = gridDim.x * blockDim.x;
  for (; i < n4; i += stride) {
    const float4 v = in[i];
    ushort4 o;
    o.x = f2bf(v.x); o.y = f2bf(v.y); o.z = f2bf(v.z); o.w = f2bf(v.w);
    out[i] = o;
  }
}

// counts[dst]++
__global__ void hist_kernel(const int* __restrict__ ei, int* __restrict__ counts) {
  int i = blockIdx.x * blockDim.x + threadIdx.x;
  if (i < N_EDGES) atomicAdd(&counts[ei[N_EDGES + i]], 1);
}

// exclusive prefix sum of counts -> cursor (single block, 1024 threads)
__global__ __launch_bounds__(1024) void scan_kernel(const int* __restrict__ counts,
                                                    int* __restrict__ cursor, int n) {
  __shared__ int wsum[16];
  __shared__ int carry;
  const int t = threadIdx.x, lane = t & 63, w = t >> 6;
  if (t == 0) carry = 0;
  __syncthreads();
  for (int base = 0; base < n; base += 1024) {
    int v = (base + t < n) ? counts[base + t] : 0;
    int s = v;
#pragma unroll
    for (int off = 1; off < 64; off <<= 1) {
      int u = __shfl_up(s, off, 64);
      if (lane >= off) s += u;
    }
    if (lane == 63) wsum[w] = s;
    __syncthreads();
    if (t < 16) {
      int ws = wsum[t];
#pragma unroll
      for (int off = 1; off < 16; off <<= 1) {
        int u = __shfl_up(ws, off, 64);
        if (lane >= off) ws += u;
      }
      wsum[t] = ws;
    }
    __syncthreads();
    const int wpre = (w == 0) ? 0 : wsum[w - 1];
    if (base + t < n) cursor[base + t] = carry + wpre + s - v;  // exclusive
    __syncthreads();
    if (t == 0) carry += wsum[15];
    __syncthreads();
  }
}

// XCD-partitioned fill: blockIdx&7 selects a 12500-wide dst range, so (with the
// round-robin block->XCD heuristic) each XCD's csr writes stay in a 1.6 MB
// slice resident in its own L2 -> dense write-back instead of 15x partial-line
// amplification. Each segment is scanned by 8 blocks (L3-resident reads).
constexpr int FILL_SEG = 4096;
__global__ __launch_bounds__(256) void fill_kernel(const int* __restrict__ ei,
                                                   int* __restrict__ cursor,
                                                   int* __restrict__ csr) {
  const int range = blockIdx.x & 7;
  const int seg   = blockIdx.x >> 3;
  const int base  = seg * FILL_SEG;
  const int lo = range * 12500, hi = lo + 12500;
#pragma unroll
  for (int j = 0; j < FILL_SEG / 256; ++j) {
    const int i = base + j * 256 + threadIdx.x;
    if (i < N_EDGES) {
      const int dst = ei[N_EDGES + i];
      if (dst >= lo && dst < hi) {
        const int pos = atomicAdd(&cursor[dst], 1);
        csr[pos] = ei[i];
      }
    }
  }
}

// out[node] = x[node] + sum_{s in csr} x[s]; bf16 rows, f32 accumulate.
// One wave per node; half-wave h covers edges beg+2j+h; lane reads 16 B
// (8 features). Unroll 4 -> 8 rows in flight per wave.
__global__ __launch_bounds__(256) void gather_agg_bf16(const ushort* __restrict__ x,
                                                       const int* __restrict__ csr,
                                                       const int* __restrict__ cursor_end,
                                                       const int* __restrict__ counts,
                                                       ushort* __restrict__ out) {
  const int node = blockIdx.x * 4 + (threadIdx.x >> 6);
  const int lane = threadIdx.x & 63;
  const int half = lane >> 5;
  const int fl   = lane & 31;
  if (node >= N_NODES) return;
  const int end = cursor_end[node];
  const int beg = end - counts[node];
  const size_t fo = (size_t)fl * 8;

  float acc[8];
#pragma unroll
  for (int j = 0; j < 8; ++j) acc[j] = 0.f;

  if (half == 0) {
    const ushort8 self = *reinterpret_cast<const ushort8*>(x + (size_t)node * D + fo);
#pragma unroll
    for (int j = 0; j < 8; ++j) acc[j] += b2f(self[j]);
  }

  int o = beg + half;
  for (; o + 6 < end; o += 8) {
    const int s0 = csr[o], s1 = csr[o + 2], s2 = csr[o + 4], s3 = csr[o + 6];
    const ushort8 v0 = *reinterpret_cast<const ushort8*>(x + (size_t)s0 * D + fo);
    const ushort8 v1 = *reinterpret_cast<const ushort8*>(x + (size_t)s1 * D + fo);
    const ushort8 v2 = *reinterpret_cast<const ushort8*>(x + (size_t)s2 * D + fo);
    const ushort8 v3 = *reinterpret_cast<const ushort8*>(x + (size_t)s3 * D + fo);
#pragma unroll
    for (int j = 0; j < 8; ++j)
      acc[j] += (b2f(v0[j]) + b2f(v1[j])) + (b2f(v2[j]) + b2f(v3[j]));
  }
  for (; o < end; o += 2) {
    const ushort8 v = *reinterpret_cast<const ushort8*>(x + (size_t)csr[o] * D + fo);
#pragma unroll
    for (int j = 0; j < 8; ++j) acc[j] += b2f(v[j]);
  }

#pragma unroll
  for (int j = 0; j < 8; ++j) acc[j] += __shfl_xor(acc[j], 32, 64);

  if (half == 0) {
    ushort8 ov;
#pragma unroll
    for (int j = 0; j < 8; ++j) ov[j] = f2bf(acc[j]);
    *reinterpret_cast<ushort8*>(out + (size_t)node * D + fo) = ov;
  }
}

// ---------------------------------------------------------------------------
// C[r][c] = relu( sum_k A[r][k]*W[c][k] + bias[c] ), bf16 in / bf16 out.
// 4 waves, 64x64 tile, K=256 staged in LDS with XOR swizzle.
// ---------------------------------------------------------------------------
__global__ __launch_bounds__(256) void gemm_mfma_bf16(const ushort* __restrict__ A,
                                                      const ushort* __restrict__ W,
                                                      const float* __restrict__ bias,
                                                      ushort* __restrict__ C,
                                                      int M) {
  __shared__ __align__(16) ushort As[64 * 256];
  __shared__ __align__(16) ushort Ws[64 * 256];

  const int t = threadIdx.x;
  const int w = t >> 6, l = t & 63;
  const int row0 = blockIdx.x * 64;
  const int col0 = blockIdx.y * 64;

  {
    const float4 zero4 = {0.f, 0.f, 0.f, 0.f};
#pragma unroll
    for (int i = 0; i < 8; ++i) {
      const int chunk = t + i * 256;
      const int r  = chunk >> 5;
      const int kb = (chunk & 31) << 4;
      const int swz = kb ^ ((r & 7) << 4);
      const int grow = row0 + r;
      float4 av = zero4;
      if (grow < M)
        av = *reinterpret_cast<const float4*>(
            reinterpret_cast<const char*>(A) + (size_t)grow * 512 + kb);
      *reinterpret_cast<float4*>(reinterpret_cast<char*>(As) + r * 512 + swz) = av;
      const float4 wv = *reinterpret_cast<const float4*>(
          reinterpret_cast<const char*>(W) + (size_t)(col0 + r) * 512 + kb);
      *reinterpret_cast<float4*>(reinterpret_cast<char*>(Ws) + r * 512 + swz) = wv;
    }
  }
  __syncthreads();

  const int g  = l >> 4;
  const int fr = l & 15;

  frag_cd acc[4];
#pragma unroll
  for (int c = 0; c < 4; ++c) {
    acc[c][0] = 0.f; acc[c][1] = 0.f; acc[c][2] = 0.f; acc[c][3] = 0.f;
  }

  const int arow = w * 16 + fr;
  const char* Asb = reinterpret_cast<const char*>(As);
  const char* Wsb = reinterpret_cast<const char*>(Ws);
#pragma unroll
  for (int ks = 0; ks < 8; ++ks) {
    const int kb = ks * 64 + g * 16;
    const frag_ab af = *reinterpret_cast<const frag_ab*>(
        Asb + arow * 512 + (kb ^ ((arow & 7) << 4)));
#pragma unroll
    for (int c = 0; c < 4; ++c) {
      const int wrow = c * 16 + fr;
      const frag_ab bf = *reinterpret_cast<const frag_ab*>(
          Wsb + wrow * 512 + (kb ^ ((wrow & 7) << 4)));
      acc[c] = __builtin_amdgcn_mfma_f32_16x16x32_bf16(af, bf, acc[c], 0, 0, 0);
    }
  }
  __syncthreads();

  ushort* Ct = As;
#pragma unroll
  for (int c = 0; c < 4; ++c) {
    const int col = c * 16 + fr;
    const float bv = bias[col0 + col];
#pragma unroll
    for (int r = 0; r < 4; ++r) {
      const int rl = w * 16 + g * 4 + r;
      Ct[rl * 64 + col] = f2bf(fmaxf(acc[c][r] + bv, 0.f));
    }
  }
  __syncthreads();
#pragma unroll
  for (int i = 0; i < 2; ++i) {
    const int chunk = t + i * 256;
    const int r  = chunk >> 3;
    const int cb = (chunk & 7) << 4;
    const int grow = row0 + r;
    if (grow < M)
      *reinterpret_cast<float4*>(reinterpret_cast<char*>(C) + (size_t)grow * 512 + col0 * 2 + cb) =
          *reinterpret_cast<const float4*>(reinterpret_cast<const char*>(Ct) + r * 128 + cb);
  }
}

// ---------------------------------------------------------------------------
// Pair head: one wave per 2 pairs. Half-wave h reads row idx[2p+h]; lane
// covers 8 features. W3 concat layout aligns: k = half*256 + fl*8 = lane*8.
// ---------------------------------------------------------------------------
__global__ __launch_bounds__(256) void pair_head_bf16(const ushort* __restrict__ h,
                                                      const int* __restrict__ idx,
                                                      const float* __restrict__ W3,
                                                      const float* __restrict__ b3,
                                                      float* __restrict__ out) {
  const int wave = (int)((blockIdx.x * (size_t)blockDim.x + threadIdx.x) >> 6);
  const int lane = threadIdx.x & 63;
  const int half = lane >> 5;
  const int fl   = lane & 31;
  const int p0 = 2 * wave, p1 = 2 * wave + 1;
  if (p0 >= N_PAIRS) return;

  const int ia = idx[2 * p0 + half];
  const int ib = idx[2 * p1 + half];
  const ushort8 va = *reinterpret_cast<const ushort8*>(h + (size_t)ia * D + fl * 8);
  const ushort8 vb = *reinterpret_cast<const ushort8*>(h + (size_t)ib * D + fl * 8);

  const float4 w0a = *reinterpret_cast<const float4*>(W3 + lane * 8);
  const float4 w0b = *reinterpret_cast<const float4*>(W3 + lane * 8 + 4);
  const float4 w1a = *reinterpret_cast<const float4*>(W3 + 512 + lane * 8);
  const float4 w1b = *reinterpret_cast<const float4*>(W3 + 512 + lane * 8 + 4);
  const float w0[8] = {w0a.x, w0a.y, w0a.z, w0a.w, w0b.x, w0b.y, w0b.z, w0b.w};
  const float w1[8] = {w1a.x, w1a.y, w1a.z, w1a.w, w1b.x, w1b.y, w1b.z, w1b.w};

  float l00 = 0.f, l01 = 0.f, l10 = 0.f, l11 = 0.f;
#pragma unroll
  for (int j = 0; j < 8; ++j) {
    const float fa = b2f(va[j]), fb = b2f(vb[j]);
    l00 += fa * w0[j]; l01 += fa * w1[j];
    l10 += fb * w0[j]; l11 += fb * w1[j];
  }
#pragma unroll
  for (int off = 32; off > 0; off >>= 1) {
    l00 += __shfl_down(l00, off, 64);
    l01 += __shfl_down(l01, off, 64);
    l10 += __shfl_down(l10, off, 64);
    l11 += __shfl_down(l11, off, 64);
  }
  if (lane == 0) {
    const float bb0 = b3[0], bb1 = b3[1];
    l00 += bb0; l01 += bb1; l10 += bb0; l11 += bb1;
    const float m0 = fmaxf(l00, l01);
    const float lse0 = m0 + logf(expf(l00 - m0) + expf(l01 - m0));
    const float m1 = fmaxf(l10, l11);
    const float lse1 = m1 + logf(expf(l10 - m1) + expf(l11 - m1));
    float4 o;
    o.x = l00 - lse0; o.y = l01 - lse0; o.z = l10 - lse1; o.w = l11 - lse1;
    *reinterpret_cast<float4*>(out + 4 * (size_t)wave) = o;
  }
}

// ---------------------------------------------------------------------------
extern "C" void kernel_launch(void* const* d_in, const int* in_sizes, int n_in,
                              void* d_out, int out_size, void* d_ws, size_t ws_size,
                              hipStream_t stream) {
  const float* x   = (const float*)d_in[0];
  const int*   ei  = (const int*)d_in[1];
  const int*   idx = (const int*)d_in[2];
  const float* W1  = (const float*)d_in[3];
  const float* b1  = (const float*)d_in[4];
  const float* W2  = (const float*)d_in[5];
  const float* b2  = (const float*)d_in[6];
  const float* W3  = (const float*)d_in[7];
  const float* b3  = (const float*)d_in[8];
  float* out = (float*)d_out;

  const size_t feat = (size_t)N_NODES * D;
  char* ws = (char*)d_ws;
  ushort* xb    = (ushort*)(ws);
  ushort* aggb  = (ushort*)(ws + 51200000);
  ushort* hb    = (ushort*)(ws + 102400000);
  ushort* W1b   = (ushort*)(ws + 153600000);
  ushort* W2b   = (ushort*)(ws + 153731072);
  int* counts   = (int*)(ws + 153862144);
  int* cursor   = (int*)(ws + 154262144);
  int* csr      = (int*)(ws + 154662144);

  const dim3 blk(256);
  const dim3 zeroGrid((N_NODES + 255) / 256);
  const dim3 edgeGrid((N_EDGES + 255) / 256);
  const int  nseg = (N_EDGES + FILL_SEG - 1) / FILL_SEG;
  const dim3 fillGrid(8 * nseg);
  const dim3 nodeGrid((N_NODES + 3) / 4);
  const dim3 gemmGrid((N_NODES + 63) / 64, D / 64);
  const dim3 pairGrid(((size_t)(N_PAIRS / 2) * 64 + 255) / 256);

  f32_to_bf16<<<dim3(4096), blk, 0, stream>>>((const float4*)x, (ushort4*)xb, (int)(feat / 4));
  f32_to_bf16<<<dim3(64), blk, 0, stream>>>((const float4*)W1, (ushort4*)W1b, 65536 / 4);
  f32_to_bf16<<<dim3(64), blk, 0, stream>>>((const float4*)W2, (ushort4*)W2b, 65536 / 4);

  zero_ints<<<zeroGrid, blk, 0, stream>>>(counts, N_NODES);
  hist_kernel<<<edgeGrid, blk, 0, stream>>>(ei, counts);
  scan_kernel<<<1, 1024, 0, stream>>>(counts, cursor, N_NODES);
  fill_kernel<<<fillGrid, blk, 0, stream>>>(ei, cursor, csr);

  gather_agg_bf16<<<nodeGrid, blk, 0, stream>>>(xb, csr, cursor, counts, aggb);
  gemm_mfma_bf16<<<gemmGrid, blk, 0, stream>>>(aggb, W1b, b1, hb, N_NODES);

  gather_agg_bf16<<<nodeGrid, blk, 0, stream>>>(hb, csr, cursor, counts, aggb);
  gemm_mfma_bf16<<<gemmGrid, blk, 0, stream>>>(aggb, W2b, b2, hb, N_NODES);

  pair_head_bf16<<<pairGrid, blk, 0, stream>>>(hb, idx, W3, b3, out);
}